// Round 4
// baseline (24914.694 us; speedup 1.0000x reference)
//
#include <hip/hip_runtime.h>
#include <math.h>

#define Tt  100
#define H1  2560
#define HID 5120
#define H2  1024
#define NB  1024   // persistent blocks (4/CU x 256 CUs)
#define GPB 5      // GRU row-groups per block = HID/NB

typedef float v4 __attribute__((ext_vector_type(4)));

// ---- flag int-offsets in ws (each on its own 64B line; first 512B memset to 0)
#define FI_HEP   0    // h epoch: value t+1 => h_t ready
#define FI_L1EP  16   // l1 epoch: value s => l1_{s-1} ready
#define FI_L2EP  32
#define FI_KGEP  48
#define FI_HCNT  64
#define FI_L2CNT 80
#define FI_KGCNT 96

// ---- float offsets in ws
#define OFF_M1X 128
#define OFF_M1Y 144
#define OFF_SPR 160
#define OFF_KG  208   // 256
#define OFF_L2  464   // 1024
#define OFF_L1  1488  // 2560
#define OFF_HB0 4048  // 5120
#define OFF_HB1 9168  // 5120 (h_{-1}=h0 lives here)

__device__ __forceinline__ void wait_ge(int* p, int v) {
  if (threadIdx.x == 0) {
    // bounded spin: ~1e7 iterations with s_sleep(8) — fails fast instead of hanging
    for (long it = 0; it < 10000000L; ++it) {
      if (__hip_atomic_load(p, __ATOMIC_RELAXED, __HIP_MEMORY_SCOPE_AGENT) >= v) break;
      __builtin_amdgcn_s_sleep(8);
    }
  }
  __syncthreads();
  __builtin_amdgcn_fence(__ATOMIC_ACQUIRE, "agent");
}

// call with all prior data stores drained (e.g. after __syncthreads())
__device__ __forceinline__ void arrive(int* cnt, int* ep, int target, int epval) {
  if (threadIdx.x == 0) {
    __builtin_amdgcn_fence(__ATOMIC_RELEASE, "agent");
    int c = __hip_atomic_fetch_add(cnt, 1, __ATOMIC_RELAXED, __HIP_MEMORY_SCOPE_AGENT);
    if (c == target - 1) {
      __builtin_amdgcn_fence(__ATOMIC_ACQUIRE, "agent");
      __hip_atomic_store(ep, epval, __ATOMIC_RELEASE, __HIP_MEMORY_SCOPE_AGENT);
    }
  }
}

__device__ __forceinline__ float dot4(v4 w, v4 x, float acc) {
  return fmaf(w.x, x.x, fmaf(w.y, x.y, fmaf(w.z, x.z, fmaf(w.w, x.w, acc))));
}

// ---------------- pre-kernel: init state, h0, kin_0, l1_0 ----------------
__global__ void k_pre(const float* __restrict__ m1_0, const float* __restrict__ h0,
                      const float* __restrict__ y, const float* __restrict__ Fm,
                      const float* __restrict__ Hm, const float* __restrict__ W1,
                      const float* __restrict__ b1, float* __restrict__ ws) {
  const int tid = threadIdx.x;
  __shared__ float s_m1x[16], s_kin[32];
  __shared__ float s_ny;
  for (int i = tid; i < HID; i += 256) ws[OFF_HB1 + i] = h0[i];
  if (tid < 16) {
    float a = 0.f;
    #pragma unroll
    for (int j = 0; j < 16; j++) a = fmaf(Fm[tid * 16 + j], m1_0[j], a);
    s_m1x[tid] = a;                       // m1x_prior_0 == sp_prior_0
  }
  __syncthreads();
  if (tid < 16) {
    float my = 0.f;
    #pragma unroll
    for (int j = 0; j < 16; j++) my = fmaf(Hm[tid * 16 + j], s_m1x[j], my);
    ws[OFF_M1X + tid] = s_m1x[tid];
    ws[OFF_M1Y + tid] = my;
    ws[OFF_SPR + tid] = s_m1x[tid];       // sp_prior_0
    s_kin[16 + tid] = y[tid * Tt + 0] - my;  // obs0_0 == m1y_0
  }
  __syncthreads();
  if (tid == 0) {
    float ny = 0.f;
    #pragma unroll
    for (int j = 0; j < 16; j++) ny += s_kin[16 + j] * s_kin[16 + j];
    s_ny = fmaxf(sqrtf(ny), 1e-12f);
  }
  __syncthreads();
  if (tid < 16) {
    s_kin[tid] = 0.f;                     // d = post - sp_post = 0
    s_kin[16 + tid] = s_kin[16 + tid] / s_ny;
  }
  __syncthreads();
  for (int r = tid; r < H1; r += 256) {
    const v4* row = (const v4*)(W1 + (size_t)r * 32);
    float acc = b1[r];
    #pragma unroll
    for (int j = 0; j < 8; j++) {
      v4 w = row[j];
      acc = fmaf(w.x, s_kin[4 * j], fmaf(w.y, s_kin[4 * j + 1],
            fmaf(w.z, s_kin[4 * j + 2], fmaf(w.w, s_kin[4 * j + 3], acc))));
    }
    ws[OFF_L1 + r] = fmaxf(acc, 0.f);
  }
  __syncthreads();
  if (tid == 0) ((int*)ws)[FI_L1EP] = 1;  // l1_0 ready (kernel boundary flushes)
}

// ---------------- persistent kernel: all 100 steps (plain launch, flag sync) ----------------
__launch_bounds__(256, 4)
__global__ void k_persist(const float* __restrict__ y, const float* __restrict__ Fm,
                          const float* __restrict__ Hm,
                          const float* __restrict__ W1, const float* __restrict__ b1,
                          const float* __restrict__ W_ih, const float* __restrict__ b_ih,
                          const float* __restrict__ W_hh, const float* __restrict__ b_hh,
                          const float* __restrict__ W2, const float* __restrict__ b2,
                          const float* __restrict__ W3, const float* __restrict__ b3,
                          float* __restrict__ out, float* __restrict__ ws) {
  const int b = blockIdx.x, tid = threadIdx.x;
  int* flags = (int*)ws;
  float* l1  = ws + OFF_L1;
  float* l2v = ws + OFF_L2;
  float* KGg = ws + OFF_KG;

  __shared__ float red[4][32];
  // block-0 small state (persists across the t loop)
  __shared__ float s_m1x[16], s_m1y[16], s_spr[16], s_post[16], s_sp[16];
  __shared__ float s_dy[16], s_d[16], s_yv[16], s_kin[32], s_nrm[2];

  if (b == 0) {
    if (tid < 16) {
      s_m1x[tid] = ws[OFF_M1X + tid];
      s_m1y[tid] = ws[OFF_M1Y + tid];
      s_spr[tid] = ws[OFF_SPR + tid];
    }
    __syncthreads();
  }

  for (int t = 0; t < Tt; ++t) {
    wait_ge(flags + FI_HEP, t);                       // h_{t-1} ready
    const float* hp = ws + ((t & 1) ? OFF_HB0 : OFF_HB1);
    float*       hc = ws + ((t & 1) ? OFF_HB1 : OFF_HB0);
    const v4* hp4 = (const v4*)hp;

    float pv[30];
    // ---- phase A: W_hh dots (only needs h_{t-1})
    #pragma unroll
    for (int k = 0; k < GPB; ++k) {
      const int i = b + k * NB;
      #pragma unroll
      for (int g = 0; g < 3; ++g) {
        const v4* row = (const v4*)(W_hh + (size_t)(i + g * HID) * HID);
        float acc = 0.f;
        for (int j = tid; j < HID / 4; j += 256) {
          v4 w = __builtin_nontemporal_load(&row[j]);
          acc = dot4(w, hp4[j], acc);
        }
        pv[k * 6 + 3 + g] = acc;
      }
    }
    // ---- phase B: W_ih dots (needs l1_t, produced by block 0's tail of t-1)
    wait_ge(flags + FI_L1EP, t + 1);
    const v4* l14 = (const v4*)l1;
    #pragma unroll
    for (int k = 0; k < GPB; ++k) {
      const int i = b + k * NB;
      #pragma unroll
      for (int g = 0; g < 3; ++g) {
        const v4* row = (const v4*)(W_ih + (size_t)(i + g * HID) * H1);
        float acc = 0.f;
        for (int j = tid; j < H1 / 4; j += 256) {
          v4 w = __builtin_nontemporal_load(&row[j]);
          acc = dot4(w, l14[j], acc);
        }
        pv[k * 6 + g] = acc;
      }
    }
    // ---- block reduce of 30 partials (wave butterfly + LDS cross-wave)
    __syncthreads();
    #pragma unroll
    for (int q = 0; q < 30; ++q) {
      float v = pv[q];
      v += __shfl_down(v, 32, 64); v += __shfl_down(v, 16, 64);
      v += __shfl_down(v, 8, 64);  v += __shfl_down(v, 4, 64);
      v += __shfl_down(v, 2, 64);  v += __shfl_down(v, 1, 64);
      pv[q] = v;
    }
    if ((tid & 63) == 0) {
      const int w = tid >> 6;
      #pragma unroll
      for (int q = 0; q < 30; ++q) red[w][q] = pv[q];
    }
    __syncthreads();
    if (tid < 30) red[0][tid] = red[0][tid] + red[1][tid] + red[2][tid] + red[3][tid];
    __syncthreads();
    if (tid < GPB) {
      const int i = b + tid * NB;
      float ir = red[0][tid * 6 + 0] + b_ih[i];
      float iz = red[0][tid * 6 + 1] + b_ih[i + HID];
      float in_ = red[0][tid * 6 + 2] + b_ih[i + 2 * HID];
      float hr = red[0][tid * 6 + 3] + b_hh[i];
      float hz = red[0][tid * 6 + 4] + b_hh[i + HID];
      float hn = red[0][tid * 6 + 5] + b_hh[i + 2 * HID];
      float r  = 1.f / (1.f + expf(-(ir + hr)));
      float z  = 1.f / (1.f + expf(-(iz + hz)));
      float nn = tanhf(in_ + r * hn);
      hc[i] = (1.f - z) * nn + z * hp[i];
    }
    __syncthreads();
    arrive(flags + FI_HCNT, flags + FI_HEP, NB * (t + 1), t + 1);

    // ---- l2: one row per block
    wait_ge(flags + FI_HEP, t + 1);
    {
      const v4* row = (const v4*)(W2 + (size_t)b * HID);
      const v4* x4 = (const v4*)hc;
      float acc = 0.f;
      for (int j = tid; j < HID / 4; j += 256)
        acc = dot4(__builtin_nontemporal_load(&row[j]), x4[j], acc);
      acc += __shfl_down(acc, 32, 64); acc += __shfl_down(acc, 16, 64);
      acc += __shfl_down(acc, 8, 64);  acc += __shfl_down(acc, 4, 64);
      acc += __shfl_down(acc, 2, 64);  acc += __shfl_down(acc, 1, 64);
      if ((tid & 63) == 0) red[tid >> 6][0] = acc;
      __syncthreads();
      if (tid == 0)
        l2v[b] = fmaxf(red[0][0] + red[1][0] + red[2][0] + red[3][0] + b2[b], 0.f);
      arrive(flags + FI_L2CNT, flags + FI_L2EP, NB * (t + 1), t + 1);
    }
    // ---- KG: blocks 0..255, one row each
    if (b < 256) {
      wait_ge(flags + FI_L2EP, t + 1);
      const v4* row = (const v4*)(W3 + (size_t)b * H2);
      const v4* x4 = (const v4*)l2v;
      v4 w = row[tid];
      float acc = dot4(w, x4[tid], 0.f);
      acc += __shfl_down(acc, 32, 64); acc += __shfl_down(acc, 16, 64);
      acc += __shfl_down(acc, 8, 64);  acc += __shfl_down(acc, 4, 64);
      acc += __shfl_down(acc, 2, 64);  acc += __shfl_down(acc, 1, 64);
      if ((tid & 63) == 0) red[tid >> 6][0] = acc;
      __syncthreads();
      if (tid == 0) KGg[b] = red[0][0] + red[1][0] + red[2][0] + red[3][0] + b3[b];
      arrive(flags + FI_KGCNT, flags + FI_KGEP, 256 * (t + 1), t + 1);
    }
    // ---- block 0: innovation t, priors t+1, kin t+1, l1 t+1
    if (b == 0) {
      wait_ge(flags + FI_KGEP, t + 1);
      if (tid < 16) s_dy[tid] = y[tid * Tt + t] - s_m1y[tid];
      __syncthreads();
      if (tid < 16) {
        float acc = s_m1x[tid];
        #pragma unroll
        for (int j = 0; j < 16; j++) acc = fmaf(KGg[tid * 16 + j], s_dy[j], acc);
        s_post[tid] = acc;
        out[tid * Tt + t] = acc;
        s_sp[tid] = s_spr[tid];           // sp_post_{t+1} = sp_prior_t
      }
      __syncthreads();
      if (t < Tt - 1) {
        if (tid < 16) {
          float a = 0.f, bb = 0.f;
          #pragma unroll
          for (int j = 0; j < 16; j++) {
            a  = fmaf(Fm[tid * 16 + j], s_post[j], a);
            bb = fmaf(Fm[tid * 16 + j], s_sp[j], bb);
          }
          s_m1x[tid] = a; s_spr[tid] = bb;
        }
        __syncthreads();
        if (tid < 16) {
          float my = 0.f, ob = 0.f;
          #pragma unroll
          for (int j = 0; j < 16; j++) {
            my = fmaf(Hm[tid * 16 + j], s_m1x[j], my);
            ob = fmaf(Hm[tid * 16 + j], s_spr[j], ob);
          }
          s_m1y[tid] = my;
          s_d[tid] = s_post[tid] - s_sp[tid];
          s_yv[tid] = y[tid * Tt + (t + 1)] - ob;
        }
        __syncthreads();
        if (tid == 0) {
          float nd = 0.f, ny = 0.f;
          #pragma unroll
          for (int j = 0; j < 16; j++) { nd += s_d[j] * s_d[j]; ny += s_yv[j] * s_yv[j]; }
          s_nrm[0] = fmaxf(sqrtf(nd), 1e-12f);
          s_nrm[1] = fmaxf(sqrtf(ny), 1e-12f);
        }
        __syncthreads();
        if (tid < 16) {
          s_kin[tid] = s_d[tid] / s_nrm[0];
          s_kin[16 + tid] = s_yv[tid] / s_nrm[1];
        }
        __syncthreads();
        for (int r = tid; r < H1; r += 256) {
          const v4* row = (const v4*)(W1 + (size_t)r * 32);
          float acc = b1[r];
          #pragma unroll
          for (int j = 0; j < 8; j++) {
            v4 w = row[j];
            acc = fmaf(w.x, s_kin[4 * j], fmaf(w.y, s_kin[4 * j + 1],
                  fmaf(w.z, s_kin[4 * j + 2], fmaf(w.w, s_kin[4 * j + 3], acc))));
          }
          l1[r] = fmaxf(acc, 0.f);
        }
        __syncthreads();
        if (tid == 0) {
          __builtin_amdgcn_fence(__ATOMIC_RELEASE, "agent");
          __hip_atomic_store(flags + FI_L1EP, t + 2, __ATOMIC_RELEASE,
                             __HIP_MEMORY_SCOPE_AGENT);
        }
      }
    }
  }
}

extern "C" void kernel_launch(void* const* d_in, const int* in_sizes, int n_in,
                              void* d_out, int out_size, void* d_ws, size_t ws_size,
                              hipStream_t stream) {
  const float* y    = (const float*)d_in[0];
  const float* Fm   = (const float*)d_in[1];
  const float* Hm   = (const float*)d_in[2];
  const float* m1_0 = (const float*)d_in[3];
  const float* h0   = (const float*)d_in[4];
  const float* W1   = (const float*)d_in[5];
  const float* b1   = (const float*)d_in[6];
  const float* W_ih = (const float*)d_in[7];
  const float* b_ih = (const float*)d_in[8];
  const float* W_hh = (const float*)d_in[9];
  const float* b_hh = (const float*)d_in[10];
  const float* W2   = (const float*)d_in[11];
  const float* b2   = (const float*)d_in[12];
  const float* W3   = (const float*)d_in[13];
  const float* b3   = (const float*)d_in[14];
  float* out = (float*)d_out;
  float* ws  = (float*)d_ws;

  (void)hipMemsetAsync(ws, 0, 512, stream);  // zero flags/counters
  k_pre<<<1, 256, 0, stream>>>(m1_0, h0, y, Fm, Hm, W1, b1, ws);
  k_persist<<<NB, 256, 0, stream>>>(y, Fm, Hm, W1, b1, W_ih, b_ih, W_hh, b_hh,
                                    W2, b2, W3, b3, out, ws);
}